// Round 13
// baseline (200.641 us; speedup 1.0000x reference)
//
#include <hip/hip_runtime.h>
#include <hip/hip_bf16.h>

#define HID 4096
#define EQKV 6144
#define NH 32
#define NKV 8
#define GQ 4
#define D 128
#define WIN 2048
#define NCH 16   // K-chunks for split-K GEMM (4096 / 256)
#define NCHK 8   // position chunks for flash-decode attention
#define CLEN (WIN / NCHK)   // 256

typedef float f4v __attribute__((ext_vector_type(4)));
typedef float f2v __attribute__((ext_vector_type(2)));

__device__ __forceinline__ float4 ntld4(const float* p) {
    const f4v v = __builtin_nontemporal_load((const f4v*)p);
    return make_float4(v.x, v.y, v.z, v.w);
}
__device__ __forceinline__ float2 ntld2(const float* p) {
    const f2v v = __builtin_nontemporal_load((const f2v*)p);
    return make_float2(v.x, v.y);
}

// ------- split-K GEMM: part[chunk][b][e] = sum_{h in chunk} X[b][h] * W[h][e]
// 8-deep W row prefetch (~4KB in flight per wave), nt loads on the W stream.
template<int E>
__global__ __launch_bounds__(256) void k_gemm_split(const float* __restrict__ X,
                                                    const float* __restrict__ W,
                                                    float* __restrict__ part) {
    __shared__ float xs[256][36];
    __shared__ float2 red[8][64][4];
    const int t = threadIdx.x;
    const int wv = t >> 6, ln = t & 63;
    const int e = blockIdx.x * 128 + ln * 2;
    const int h0 = blockIdx.y * 256;

    {   // stage X[0..32)[h0..h0+256) -> xs[hl][b]
        const int bs = t >> 3, hs = (t & 7) * 32;
#pragma unroll
        for (int i = 0; i < 8; ++i) {
            const float4 v = *(const float4*)&X[(size_t)bs * HID + h0 + hs + i * 4];
            xs[hs + i * 4 + 0][bs] = v.x;
            xs[hs + i * 4 + 1][bs] = v.y;
            xs[hs + i * 4 + 2][bs] = v.z;
            xs[hs + i * 4 + 3][bs] = v.w;
        }
    }
    __syncthreads();

    float2 acc[32];
#pragma unroll
    for (int i = 0; i < 32; ++i) acc[i] = make_float2(0.f, 0.f);

    const float* Wp = W + (size_t)(h0 + wv * 64) * E + e;
    const int hl0 = wv * 64;
    float2 wb[8];
#pragma unroll
    for (int i = 0; i < 8; ++i) wb[i] = ntld2(Wp + (size_t)i * E);
    Wp += (size_t)8 * E;

    for (int hh = 0; hh < 64; hh += 8) {
        float2 wc[8];
#pragma unroll
        for (int i = 0; i < 8; ++i) wc[i] = wb[i];
        if (hh + 8 < 64) {
#pragma unroll
            for (int i = 0; i < 8; ++i) wb[i] = ntld2(Wp + (size_t)i * E);
            Wp += (size_t)8 * E;
        }
#pragma unroll
        for (int i = 0; i < 8; ++i) {
            const float wx = wc[i].x, wy = wc[i].y;
            const int row = hl0 + hh + i;
#pragma unroll
            for (int q = 0; q < 8; ++q) {
                const float4 xv = *(const float4*)&xs[row][q * 4];
                acc[q * 4 + 0].x = fmaf(xv.x, wx, acc[q * 4 + 0].x);
                acc[q * 4 + 0].y = fmaf(xv.x, wy, acc[q * 4 + 0].y);
                acc[q * 4 + 1].x = fmaf(xv.y, wx, acc[q * 4 + 1].x);
                acc[q * 4 + 1].y = fmaf(xv.y, wy, acc[q * 4 + 1].y);
                acc[q * 4 + 2].x = fmaf(xv.z, wx, acc[q * 4 + 2].x);
                acc[q * 4 + 2].y = fmaf(xv.z, wy, acc[q * 4 + 2].y);
                acc[q * 4 + 3].x = fmaf(xv.w, wx, acc[q * 4 + 3].x);
                acc[q * 4 + 3].y = fmaf(xv.w, wy, acc[q * 4 + 3].y);
            }
        }
    }

    for (int r = 0; r < 4; ++r) {
#pragma unroll
        for (int j = 0; j < 8; ++j) red[j][ln][wv] = acc[r * 8 + j];
        __syncthreads();
#pragma unroll
        for (int it = 0; it < 2; ++it) {
            const int item = t + it * 256;
            const int ln2 = item & 63, j2 = item >> 6;
            const float2 a0 = red[j2][ln2][0], a1 = red[j2][ln2][1];
            const float2 a2 = red[j2][ln2][2], a3 = red[j2][ln2][3];
            const float2 s = make_float2((a0.x + a1.x) + (a2.x + a3.x),
                                         (a0.y + a1.y) + (a2.y + a3.y));
            const int b2 = r * 8 + j2;
            const int e2 = blockIdx.x * 128 + ln2 * 2;
            *(float2*)(part + ((size_t)blockIdx.y * 32 + b2) * E + e2) = s;
        }
        __syncthreads();
    }
}

// ---------------- final reduce of wo-GEMM partials -> d_out ----------------
__global__ void k_reduce_f32(const float* __restrict__ part,
                             float* __restrict__ out, const int n) {
    const int i4 = (blockIdx.x * 256 + threadIdx.x) * 4;
    if (i4 >= n) return;
    float4 s = make_float4(0.f, 0.f, 0.f, 0.f);
#pragma unroll
    for (int c = 0; c < NCH; ++c) {
        const float4 p = *(const float4*)(part + (size_t)c * n + i4);
        s.x += p.x; s.y += p.y; s.z += p.z; s.w += p.w;
    }
    *(float4*)(out + i4) = s;
}

// ------- fused: reduce qkv partials + rope (q,k) + v extract -------
__global__ __launch_bounds__(128) void k_finish(
        const float* __restrict__ part, const float* __restrict__ R,
        float* __restrict__ q_rot, float* __restrict__ k_rot,
        float* __restrict__ v_new) {
    __shared__ float sq[D];
    const int bid = blockIdx.x;
    const int b = bid / 48, u = bid % 48;
    const int tid = threadIdx.x;
    const int e0 = u * D;

    float s = 0.f;
#pragma unroll
    for (int c = 0; c < NCH; ++c)
        s += part[((size_t)c * 32 + b) * EQKV + e0 + tid];

    if (u < 40) {   // q or k: rope
        sq[tid] = s;
        __syncthreads();
        float acc = 0.f;
        for (int d = 0; d < D; d += 4) {
            const float r0 = R[(size_t)(d + 0) * D + tid];
            const float r1 = R[(size_t)(d + 1) * D + tid];
            const float r2 = R[(size_t)(d + 2) * D + tid];
            const float r3 = R[(size_t)(d + 3) * D + tid];
            acc = fmaf(sq[d + 0], r0, acc);
            acc = fmaf(sq[d + 1], r1, acc);
            acc = fmaf(sq[d + 2], r2, acc);
            acc = fmaf(sq[d + 3], r3, acc);
        }
        if (u < 32) q_rot[((size_t)b * NH + u) * D + tid] = acc;
        else        k_rot[((size_t)b * NKV + (u - 32)) * D + tid] = acc;
    } else {        // v: plain reduce
        v_new[((size_t)b * NKV + (u - 40)) * D + tid] = s;
    }
}

// ------- flash-decode attention partial: one block per (b, kv, chunk) -------
// R9 structure; nt loads on the K and V streams.
__global__ __launch_bounds__(256) void k_attn_part(
        const float* __restrict__ q_rot, const float* __restrict__ k_rot,
        const float* __restrict__ v_new,
        const float* __restrict__ cache_k, const float* __restrict__ cache_v,
        const int* __restrict__ p_start, const int* __restrict__ p_cur,
        float* __restrict__ pacc, float* __restrict__ pm, float* __restrict__ psum) {
    __shared__ float qs[4 * D];
    __shared__ float kn[D];
    __shared__ float vn[D];
    __shared__ float S[4 * CLEN];
    __shared__ float sm_m[4], sm_s[4];
    __shared__ float red[4 * 4 * D];

    const int t = threadIdx.x;
    const int bid = blockIdx.x;
    const int bkv = bid >> 3, c = bid & (NCHK - 1);
    const int b = bkv >> 3, kv = bkv & 7;
    const int l = t & 63, w = t >> 6;       // w in 0..3
    const int ls = min(p_start[0] + 1, WIN);
    const int cur = p_cur[0];
    const int p0 = c * CLEN;
    const int pend = min(ls, p0 + CLEN);
    const int cnt = pend - p0;
    const bool full = (cnt == CLEN);

    {   // stage q (4 heads), new k, new v
        const float* qsrc = q_rot + ((size_t)b * NH + kv * GQ) * D;
        qs[t] = qsrc[t];
        qs[t + 256] = qsrc[t + 256];
        if (t < 128) kn[t] = k_rot[((size_t)b * NKV + kv) * D + t];
        else vn[t - 128] = v_new[((size_t)b * NKV + kv) * D + (t - 128)];
    }
    __syncthreads();

    const float scale = 0.08838834764831845f;   // 1/sqrt(128)
    const size_t base = (size_t)bkv * WIN * D;

    // ---- pass 1: scores. 8 lanes per row (lane owns 16 d's); 32 rows/iter. ----
    {
        const int sub = l & 7, r = l >> 3;
        const int d0 = sub * 16;
        const int row0 = w * 8 + r;             // 0..31
        float qreg[4][16];
#pragma unroll
        for (int g = 0; g < 4; ++g)
#pragma unroll
            for (int j = 0; j < 16; ++j) qreg[g][j] = qs[g * D + d0 + j] * scale;

        if (full) {
            const float* kp = cache_k + base + (size_t)(p0 + row0) * D + d0;
            float4 A0 = ntld4(kp);
            float4 A1 = ntld4(kp + 4);
            float4 A2 = ntld4(kp + 8);
            float4 A3 = ntld4(kp + 12);
            int pl = row0;
            for (int it = 0; it < CLEN / 32; ++it) {
                const float4 a0 = A0, a1 = A1, a2 = A2, a3 = A3;
                kp += (size_t)32 * D;
                if (it + 1 < CLEN / 32) {
                    A0 = ntld4(kp);
                    A1 = ntld4(kp + 4);
                    A2 = ntld4(kp + 8);
                    A3 = ntld4(kp + 12);
                }
                const float kk[16] = {a0.x, a0.y, a0.z, a0.w, a1.x, a1.y, a1.z, a1.w,
                                      a2.x, a2.y, a2.z, a2.w, a3.x, a3.y, a3.z, a3.w};
                float s4[4] = {0.f, 0.f, 0.f, 0.f};
#pragma unroll
                for (int g = 0; g < 4; ++g)
#pragma unroll
                    for (int j = 0; j < 16; ++j) s4[g] = fmaf(qreg[g][j], kk[j], s4[g]);
#pragma unroll
                for (int off = 1; off < 8; off <<= 1)
#pragma unroll
                    for (int g = 0; g < 4; ++g) s4[g] += __shfl_xor(s4[g], off, 8);
                if (sub == 0) {
                    S[0 * CLEN + pl] = s4[0];
                    S[1 * CLEN + pl] = s4[1];
                    S[2 * CLEN + pl] = s4[2];
                    S[3 * CLEN + pl] = s4[3];
                }
                pl += 32;
            }
        } else {
            for (int it = 0; it < CLEN / 32; ++it) {
                const int p = p0 + it * 32 + row0;
                if (p < pend) {
                    const float* kp = cache_k + base + (size_t)p * D + d0;
                    const float4 a0 = ntld4(kp);
                    const float4 a1 = ntld4(kp + 4);
                    const float4 a2 = ntld4(kp + 8);
                    const float4 a3 = ntld4(kp + 12);
                    const float kk[16] = {a0.x, a0.y, a0.z, a0.w, a1.x, a1.y, a1.z, a1.w,
                                          a2.x, a2.y, a2.z, a2.w, a3.x, a3.y, a3.z, a3.w};
                    float s4[4] = {0.f, 0.f, 0.f, 0.f};
#pragma unroll
                    for (int g = 0; g < 4; ++g)
#pragma unroll
                        for (int j = 0; j < 16; ++j) s4[g] = fmaf(qreg[g][j], kk[j], s4[g]);
#pragma unroll
                    for (int off = 1; off < 8; off <<= 1)
#pragma unroll
                        for (int g = 0; g < 4; ++g) s4[g] += __shfl_xor(s4[g], off, 8);
                    if (sub == 0) {
                        const int pl = p - p0;
                        S[0 * CLEN + pl] = s4[0];
                        S[1 * CLEN + pl] = s4[1];
                        S[2 * CLEN + pl] = s4[2];
                        S[3 * CLEN + pl] = s4[3];
                    }
                }
            }
        }
    }
    __syncthreads();

    // ---- patch position cur with the NEW k ----
    if (cur >= p0 && cur < pend && t < 4) {
        float a = 0.f;
        for (int d = 0; d < D; ++d) a = fmaf(qs[t * D + d], kn[d], a);
        S[t * CLEN + cur - p0] = a * scale;
    }
    __syncthreads();

    // ---- partial softmax (waves 0..3, one per g) ----
    {
        float m = -1e30f;
        for (int p = l; p < cnt; p += 64) m = fmaxf(m, S[w * CLEN + p]);
#pragma unroll
        for (int off = 32; off; off >>= 1) m = fmaxf(m, __shfl_xor(m, off, 64));
        float sum = 0.f;
        for (int p = l; p < cnt; p += 64) {
            const float e = __expf(S[w * CLEN + p] - m);
            S[w * CLEN + p] = e;
            sum += e;
        }
#pragma unroll
        for (int off = 32; off; off >>= 1) sum += __shfl_xor(sum, off, 64);
        if (l == 0) { sm_m[w] = m; sm_s[w] = sum; }
    }
    __syncthreads();

    // ---- pass 2: PV (unnormalized). thread owns 8 d's, strides p by 16. ----
    {
        const int s = t & 15, pt = t >> 4;      // pt 0..15
        const int d0 = s * 8;
        float acc[4][8];
#pragma unroll
        for (int g = 0; g < 4; ++g)
#pragma unroll
            for (int j = 0; j < 8; ++j) acc[g][j] = 0.f;

        if (full) {
            const float* vp = cache_v + base + (size_t)(p0 + pt) * D + d0;
            float4 A = ntld4(vp);
            float4 C = ntld4(vp + 4);
            int pl = pt;
            for (int it = 0; it < CLEN / 16; ++it) {
                const float4 a = A, cc = C;
                vp += (size_t)16 * D;
                if (it + 1 < CLEN / 16) {
                    A = ntld4(vp);
                    C = ntld4(vp + 4);
                }
                const float vv[8] = {a.x, a.y, a.z, a.w, cc.x, cc.y, cc.z, cc.w};
                const float s0 = S[0 * CLEN + pl], s1 = S[1 * CLEN + pl];
                const float s2 = S[2 * CLEN + pl], s3 = S[3 * CLEN + pl];
#pragma unroll
                for (int j = 0; j < 8; ++j) {
                    acc[0][j] = fmaf(s0, vv[j], acc[0][j]);
                    acc[1][j] = fmaf(s1, vv[j], acc[1][j]);
                    acc[2][j] = fmaf(s2, vv[j], acc[2][j]);
                    acc[3][j] = fmaf(s3, vv[j], acc[3][j]);
                }
                pl += 16;
            }
            // post-hoc fix of position cur: acc += S[cur]*(vn - v_cached)
            if (cur >= p0 && cur < pend && pt == ((cur - p0) & 15)) {
                const float* vc = cache_v + base + (size_t)cur * D + d0;
                const float4 a = *(const float4*)vc;
                const float4 cc = *(const float4*)(vc + 4);
                const float vv[8] = {a.x, a.y, a.z, a.w, cc.x, cc.y, cc.z, cc.w};
                const int pl2 = cur - p0;
                const float s0 = S[0 * CLEN + pl2], s1 = S[1 * CLEN + pl2];
                const float s2 = S[2 * CLEN + pl2], s3 = S[3 * CLEN + pl2];
#pragma unroll
                for (int j = 0; j < 8; ++j) {
                    const float dv = vn[d0 + j] - vv[j];
                    acc[0][j] = fmaf(s0, dv, acc[0][j]);
                    acc[1][j] = fmaf(s1, dv, acc[1][j]);
                    acc[2][j] = fmaf(s2, dv, acc[2][j]);
                    acc[3][j] = fmaf(s3, dv, acc[3][j]);
                }
            }
        } else {
            float vn8[8];
#pragma unroll
            for (int j = 0; j < 8; ++j) vn8[j] = vn[d0 + j];
            for (int i = 0; i < CLEN / 16; ++i) {
                const int p = p0 + i * 16 + pt;
                if (p < pend) {
                    const float4 a = ntld4(cache_v + base + (size_t)p * D + d0);
                    const float4 cc = ntld4(cache_v + base + (size_t)p * D + d0 + 4);
                    float vv[8] = {a.x, a.y, a.z, a.w, cc.x, cc.y, cc.z, cc.w};
                    if (p == cur) {
#pragma unroll
                        for (int j = 0; j < 8; ++j) vv[j] = vn8[j];
                    }
                    const int pl = p - p0;
                    const float s0 = S[0 * CLEN + pl], s1 = S[1 * CLEN + pl];
                    const float s2 = S[2 * CLEN + pl], s3 = S[3 * CLEN + pl];
#pragma unroll
                    for (int j = 0; j < 8; ++j) {
                        acc[0][j] = fmaf(s0, vv[j], acc[0][j]);
                        acc[1][j] = fmaf(s1, vv[j], acc[1][j]);
                        acc[2][j] = fmaf(s2, vv[j], acc[2][j]);
                        acc[3][j] = fmaf(s3, vv[j], acc[3][j]);
                    }
                }
            }
        }
        // reduce over the 4 in-wave pt-groups (lane bits 4,5)
#pragma unroll
        for (int off = 16; off <= 32; off <<= 1)
#pragma unroll
            for (int g = 0; g < 4; ++g)
#pragma unroll
                for (int j = 0; j < 8; ++j)
                    acc[g][j] += __shfl_xor(acc[g][j], off, 64);
        if (l < 16) {
#pragma unroll
            for (int g = 0; g < 4; ++g)
#pragma unroll
                for (int j = 0; j < 8; ++j)
                    red[(w * 4 + g) * D + l * 8 + j] = acc[g][j];
        }
    }
    __syncthreads();

    {   // cross-wave reduce + write partials (each thread covers 2 heads)
        const int d = t & 127, half = t >> 7;
#pragma unroll
        for (int gi = 0; gi < 2; ++gi) {
            const int g = half + gi * 2;
            float sum = 0.f;
#pragma unroll
            for (int w4 = 0; w4 < 4; ++w4) sum += red[(w4 * 4 + g) * D + d];
            const int hidx = bkv * GQ + g;
            pacc[((size_t)hidx * NCHK + c) * D + d] = sum;
            if (d == 0) {
                pm[hidx * NCHK + c]   = sm_m[g];
                psum[hidx * NCHK + c] = sm_s[g];
            }
        }
    }
}

// ------- combine partial chunks: one block per (b, kv), 512 threads -------
__global__ __launch_bounds__(512) void k_attn_combine(
        const float* __restrict__ pacc, const float* __restrict__ pm,
        const float* __restrict__ psum, float* __restrict__ attn_out) {
    const int t = threadIdx.x;
    const int bkv = blockIdx.x;
    const int b = bkv >> 3, kv = bkv & 7;
    const int g = t >> 7, d = t & 127;
    const int hidx = bkv * GQ + g;

    float mm[NCHK];
    float m = -1e30f;
#pragma unroll
    for (int c = 0; c < NCHK; ++c) {
        mm[c] = pm[hidx * NCHK + c];
        m = fmaxf(m, mm[c]);
    }
    float tot = 0.f, acc = 0.f;
#pragma unroll
    for (int c = 0; c < NCHK; ++c) {
        const float wgt = __expf(mm[c] - m);
        tot = fmaf(psum[hidx * NCHK + c], wgt, tot);
        acc = fmaf(pacc[((size_t)hidx * NCHK + c) * D + d], wgt, acc);
    }
    attn_out[(size_t)b * HID + (kv * GQ + g) * D + d] = acc / tot;
}

// ---------------- host launch ----------------
extern "C" void kernel_launch(void* const* d_in, const int* in_sizes, int n_in,
                              void* d_out, int out_size, void* d_ws, size_t ws_size,
                              hipStream_t stream) {
    const float* x    = (const float*)d_in[0];
    const float* wqkv = (const float*)d_in[1];
    const float* wo   = (const float*)d_in[2];
    const float* rot  = (const float*)d_in[3];
    const float* ck   = (const float*)d_in[4];
    const float* cv   = (const float*)d_in[5];
    const int*   sp   = (const int*)d_in[6];
    const int*   cp   = (const int*)d_in[7];

    float* ws     = (float*)d_ws;
    float* q_rot  = ws;                     // 32*32*128 = 131072
    float* k_rot  = ws + 131072;            // 32*8*128  = 32768
    float* v_new  = ws + 163840;            // 32*8*128  = 32768
    float* attn_o = ws + 196608;            // 32*4096   = 131072
    float* part   = ws + 327680;            // NCH*32*6144 = 3145728 (GEMM partials)
    // attention partials alias the part region (disjoint in time):
    float* pacc   = part;                   // 1024*8*128 = 1048576
    float* pm     = part + 1048576;         // 8192
    float* psum   = part + 1056768;         // 8192

    k_gemm_split<EQKV><<<dim3(EQKV / 128, NCH), 256, 0, stream>>>(x, wqkv, part);
    k_finish<<<32 * 48, 128, 0, stream>>>(part, rot, q_rot, k_rot, v_new);
    k_attn_part<<<256 * NCHK, 256, 0, stream>>>(q_rot, k_rot, v_new, ck, cv,
                                                sp, cp, pacc, pm, psum);
    k_attn_combine<<<256, 512, 0, stream>>>(pacc, pm, psum, attn_o);
    k_gemm_split<HID><<<dim3(HID / 128, NCH), 256, 0, stream>>>(attn_o, wo, part);
    k_reduce_f32<<<128, 256, 0, stream>>>(part, (float*)d_out, 32 * HID);
}

// Round 14
// 174.920 us; speedup vs baseline: 1.1470x; 1.1470x over previous
//
#include <hip/hip_runtime.h>
#include <hip/hip_bf16.h>

#define HID 4096
#define EQKV 6144
#define NH 32
#define NKV 8
#define GQ 4
#define D 128
#define WIN 2048
#define NCH 16   // K-chunks for split-K GEMM (4096 / 256)
#define NCHK 8   // position chunks for flash-decode attention
#define CLEN (WIN / NCHK)   // 256

// ------- split-K GEMM: part[chunk][b][e] = sum_{h in chunk} X[b][h] * W[h][e]
// 8-deep W row prefetch (~4KB in flight per wave).
template<int E>
__global__ __launch_bounds__(256) void k_gemm_split(const float* __restrict__ X,
                                                    const float* __restrict__ W,
                                                    float* __restrict__ part) {
    __shared__ float xs[256][36];
    __shared__ float2 red[8][64][4];
    const int t = threadIdx.x;
    const int wv = t >> 6, ln = t & 63;
    const int e = blockIdx.x * 128 + ln * 2;
    const int h0 = blockIdx.y * 256;

    {   // stage X[0..32)[h0..h0+256) -> xs[hl][b]
        const int bs = t >> 3, hs = (t & 7) * 32;
#pragma unroll
        for (int i = 0; i < 8; ++i) {
            const float4 v = *(const float4*)&X[(size_t)bs * HID + h0 + hs + i * 4];
            xs[hs + i * 4 + 0][bs] = v.x;
            xs[hs + i * 4 + 1][bs] = v.y;
            xs[hs + i * 4 + 2][bs] = v.z;
            xs[hs + i * 4 + 3][bs] = v.w;
        }
    }
    __syncthreads();

    float2 acc[32];
#pragma unroll
    for (int i = 0; i < 32; ++i) acc[i] = make_float2(0.f, 0.f);

    const float* Wp = W + (size_t)(h0 + wv * 64) * E + e;
    const int hl0 = wv * 64;
    float2 wb[8];
#pragma unroll
    for (int i = 0; i < 8; ++i) wb[i] = *(const float2*)(Wp + (size_t)i * E);
    Wp += (size_t)8 * E;

    for (int hh = 0; hh < 64; hh += 8) {
        float2 wc[8];
#pragma unroll
        for (int i = 0; i < 8; ++i) wc[i] = wb[i];
        if (hh + 8 < 64) {
#pragma unroll
            for (int i = 0; i < 8; ++i) wb[i] = *(const float2*)(Wp + (size_t)i * E);
            Wp += (size_t)8 * E;
        }
#pragma unroll
        for (int i = 0; i < 8; ++i) {
            const float wx = wc[i].x, wy = wc[i].y;
            const int row = hl0 + hh + i;
#pragma unroll
            for (int q = 0; q < 8; ++q) {
                const float4 xv = *(const float4*)&xs[row][q * 4];
                acc[q * 4 + 0].x = fmaf(xv.x, wx, acc[q * 4 + 0].x);
                acc[q * 4 + 0].y = fmaf(xv.x, wy, acc[q * 4 + 0].y);
                acc[q * 4 + 1].x = fmaf(xv.y, wx, acc[q * 4 + 1].x);
                acc[q * 4 + 1].y = fmaf(xv.y, wy, acc[q * 4 + 1].y);
                acc[q * 4 + 2].x = fmaf(xv.z, wx, acc[q * 4 + 2].x);
                acc[q * 4 + 2].y = fmaf(xv.z, wy, acc[q * 4 + 2].y);
                acc[q * 4 + 3].x = fmaf(xv.w, wx, acc[q * 4 + 3].x);
                acc[q * 4 + 3].y = fmaf(xv.w, wy, acc[q * 4 + 3].y);
            }
        }
    }

    for (int r = 0; r < 4; ++r) {
#pragma unroll
        for (int j = 0; j < 8; ++j) red[j][ln][wv] = acc[r * 8 + j];
        __syncthreads();
#pragma unroll
        for (int it = 0; it < 2; ++it) {
            const int item = t + it * 256;
            const int ln2 = item & 63, j2 = item >> 6;
            const float2 a0 = red[j2][ln2][0], a1 = red[j2][ln2][1];
            const float2 a2 = red[j2][ln2][2], a3 = red[j2][ln2][3];
            const float2 s = make_float2((a0.x + a1.x) + (a2.x + a3.x),
                                         (a0.y + a1.y) + (a2.y + a3.y));
            const int b2 = r * 8 + j2;
            const int e2 = blockIdx.x * 128 + ln2 * 2;
            *(float2*)(part + ((size_t)blockIdx.y * 32 + b2) * E + e2) = s;
        }
        __syncthreads();
    }
}

// ---------------- final reduce of wo-GEMM partials -> d_out ----------------
__global__ void k_reduce_f32(const float* __restrict__ part,
                             float* __restrict__ out, const int n) {
    const int i4 = (blockIdx.x * 256 + threadIdx.x) * 4;
    if (i4 >= n) return;
    float4 s = make_float4(0.f, 0.f, 0.f, 0.f);
#pragma unroll
    for (int c = 0; c < NCH; ++c) {
        const float4 p = *(const float4*)(part + (size_t)c * n + i4);
        s.x += p.x; s.y += p.y; s.z += p.z; s.w += p.w;
    }
    *(float4*)(out + i4) = s;
}

// ------- fused: reduce qkv partials + rope (q,k) + v extract -------
__global__ __launch_bounds__(128) void k_finish(
        const float* __restrict__ part, const float* __restrict__ R,
        float* __restrict__ q_rot, float* __restrict__ k_rot,
        float* __restrict__ v_new) {
    __shared__ float sq[D];
    const int bid = blockIdx.x;
    const int b = bid / 48, u = bid % 48;
    const int tid = threadIdx.x;
    const int e0 = u * D;

    float s = 0.f;
#pragma unroll
    for (int c = 0; c < NCH; ++c)
        s += part[((size_t)c * 32 + b) * EQKV + e0 + tid];

    if (u < 40) {   // q or k: rope
        sq[tid] = s;
        __syncthreads();
        float acc = 0.f;
        for (int d = 0; d < D; d += 4) {
            const float r0 = R[(size_t)(d + 0) * D + tid];
            const float r1 = R[(size_t)(d + 1) * D + tid];
            const float r2 = R[(size_t)(d + 2) * D + tid];
            const float r3 = R[(size_t)(d + 3) * D + tid];
            acc = fmaf(sq[d + 0], r0, acc);
            acc = fmaf(sq[d + 1], r1, acc);
            acc = fmaf(sq[d + 2], r2, acc);
            acc = fmaf(sq[d + 3], r3, acc);
        }
        if (u < 32) q_rot[((size_t)b * NH + u) * D + tid] = acc;
        else        k_rot[((size_t)b * NKV + (u - 32)) * D + tid] = acc;
    } else {        // v: plain reduce
        v_new[((size_t)b * NKV + (u - 40)) * D + tid] = s;
    }
}

// ------- flash-decode attention partial: one block per (b, kv, chunk) -------
// 256 threads = 4 waves.
__global__ __launch_bounds__(256) void k_attn_part(
        const float* __restrict__ q_rot, const float* __restrict__ k_rot,
        const float* __restrict__ v_new,
        const float* __restrict__ cache_k, const float* __restrict__ cache_v,
        const int* __restrict__ p_start, const int* __restrict__ p_cur,
        float* __restrict__ pacc, float* __restrict__ pm, float* __restrict__ psum) {
    __shared__ float qs[4 * D];
    __shared__ float kn[D];
    __shared__ float vn[D];
    __shared__ float S[4 * CLEN];
    __shared__ float sm_m[4], sm_s[4];
    __shared__ float red[4 * 4 * D];

    const int t = threadIdx.x;
    const int bid = blockIdx.x;
    const int bkv = bid >> 3, c = bid & (NCHK - 1);
    const int b = bkv >> 3, kv = bkv & 7;
    const int l = t & 63, w = t >> 6;       // w in 0..3
    const int ls = min(p_start[0] + 1, WIN);
    const int cur = p_cur[0];
    const int p0 = c * CLEN;
    const int pend = min(ls, p0 + CLEN);
    const int cnt = pend - p0;
    const bool full = (cnt == CLEN);

    {   // stage q (4 heads), new k, new v
        const float* qsrc = q_rot + ((size_t)b * NH + kv * GQ) * D;
        qs[t] = qsrc[t];
        qs[t + 256] = qsrc[t + 256];
        if (t < 128) kn[t] = k_rot[((size_t)b * NKV + kv) * D + t];
        else vn[t - 128] = v_new[((size_t)b * NKV + kv) * D + (t - 128)];
    }
    __syncthreads();

    const float scale = 0.08838834764831845f;   // 1/sqrt(128)
    const size_t base = (size_t)bkv * WIN * D;

    // ---- pass 1: scores. 8 lanes per row (lane owns 16 d's); 32 rows/iter. ----
    {
        const int sub = l & 7, r = l >> 3;
        const int d0 = sub * 16;
        const int row0 = w * 8 + r;             // 0..31
        float qreg[4][16];
#pragma unroll
        for (int g = 0; g < 4; ++g)
#pragma unroll
            for (int j = 0; j < 16; ++j) qreg[g][j] = qs[g * D + d0 + j] * scale;

        if (full) {
            const float* kp = cache_k + base + (size_t)(p0 + row0) * D + d0;
            float4 A0 = *(const float4*)kp;
            float4 A1 = *(const float4*)(kp + 4);
            float4 A2 = *(const float4*)(kp + 8);
            float4 A3 = *(const float4*)(kp + 12);
            int pl = row0;
            for (int it = 0; it < CLEN / 32; ++it) {
                const float4 a0 = A0, a1 = A1, a2 = A2, a3 = A3;
                kp += (size_t)32 * D;
                if (it + 1 < CLEN / 32) {
                    A0 = *(const float4*)kp;
                    A1 = *(const float4*)(kp + 4);
                    A2 = *(const float4*)(kp + 8);
                    A3 = *(const float4*)(kp + 12);
                }
                const float kk[16] = {a0.x, a0.y, a0.z, a0.w, a1.x, a1.y, a1.z, a1.w,
                                      a2.x, a2.y, a2.z, a2.w, a3.x, a3.y, a3.z, a3.w};
                float s4[4] = {0.f, 0.f, 0.f, 0.f};
#pragma unroll
                for (int g = 0; g < 4; ++g)
#pragma unroll
                    for (int j = 0; j < 16; ++j) s4[g] = fmaf(qreg[g][j], kk[j], s4[g]);
#pragma unroll
                for (int off = 1; off < 8; off <<= 1)
#pragma unroll
                    for (int g = 0; g < 4; ++g) s4[g] += __shfl_xor(s4[g], off, 8);
                if (sub == 0) {
                    S[0 * CLEN + pl] = s4[0];
                    S[1 * CLEN + pl] = s4[1];
                    S[2 * CLEN + pl] = s4[2];
                    S[3 * CLEN + pl] = s4[3];
                }
                pl += 32;
            }
        } else {
            for (int it = 0; it < CLEN / 32; ++it) {
                const int p = p0 + it * 32 + row0;
                if (p < pend) {
                    const float* kp = cache_k + base + (size_t)p * D + d0;
                    const float4 a0 = *(const float4*)kp;
                    const float4 a1 = *(const float4*)(kp + 4);
                    const float4 a2 = *(const float4*)(kp + 8);
                    const float4 a3 = *(const float4*)(kp + 12);
                    const float kk[16] = {a0.x, a0.y, a0.z, a0.w, a1.x, a1.y, a1.z, a1.w,
                                          a2.x, a2.y, a2.z, a2.w, a3.x, a3.y, a3.z, a3.w};
                    float s4[4] = {0.f, 0.f, 0.f, 0.f};
#pragma unroll
                    for (int g = 0; g < 4; ++g)
#pragma unroll
                        for (int j = 0; j < 16; ++j) s4[g] = fmaf(qreg[g][j], kk[j], s4[g]);
#pragma unroll
                    for (int off = 1; off < 8; off <<= 1)
#pragma unroll
                        for (int g = 0; g < 4; ++g) s4[g] += __shfl_xor(s4[g], off, 8);
                    if (sub == 0) {
                        const int pl = p - p0;
                        S[0 * CLEN + pl] = s4[0];
                        S[1 * CLEN + pl] = s4[1];
                        S[2 * CLEN + pl] = s4[2];
                        S[3 * CLEN + pl] = s4[3];
                    }
                }
            }
        }
    }
    __syncthreads();

    // ---- patch position cur with the NEW k ----
    if (cur >= p0 && cur < pend && t < 4) {
        float a = 0.f;
        for (int d = 0; d < D; ++d) a = fmaf(qs[t * D + d], kn[d], a);
        S[t * CLEN + cur - p0] = a * scale;
    }
    __syncthreads();

    // ---- partial softmax (waves 0..3, one per g) ----
    {
        float m = -1e30f;
        for (int p = l; p < cnt; p += 64) m = fmaxf(m, S[w * CLEN + p]);
#pragma unroll
        for (int off = 32; off; off >>= 1) m = fmaxf(m, __shfl_xor(m, off, 64));
        float sum = 0.f;
        for (int p = l; p < cnt; p += 64) {
            const float e = __expf(S[w * CLEN + p] - m);
            S[w * CLEN + p] = e;
            sum += e;
        }
#pragma unroll
        for (int off = 32; off; off >>= 1) sum += __shfl_xor(sum, off, 64);
        if (l == 0) { sm_m[w] = m; sm_s[w] = sum; }
    }
    __syncthreads();

    // ---- pass 2: PV (unnormalized). thread owns 8 d's, strides p by 16. ----
    {
        const int s = t & 15, pt = t >> 4;      // pt 0..15
        const int d0 = s * 8;
        float acc[4][8];
#pragma unroll
        for (int g = 0; g < 4; ++g)
#pragma unroll
            for (int j = 0; j < 8; ++j) acc[g][j] = 0.f;

        if (full) {
            const float* vp = cache_v + base + (size_t)(p0 + pt) * D + d0;
            float4 A = *(const float4*)vp;
            float4 C = *(const float4*)(vp + 4);
            int pl = pt;
            for (int it = 0; it < CLEN / 16; ++it) {
                const float4 a = A, cc = C;
                vp += (size_t)16 * D;
                if (it + 1 < CLEN / 16) {
                    A = *(const float4*)vp;
                    C = *(const float4*)(vp + 4);
                }
                const float vv[8] = {a.x, a.y, a.z, a.w, cc.x, cc.y, cc.z, cc.w};
                const float s0 = S[0 * CLEN + pl], s1 = S[1 * CLEN + pl];
                const float s2 = S[2 * CLEN + pl], s3 = S[3 * CLEN + pl];
#pragma unroll
                for (int j = 0; j < 8; ++j) {
                    acc[0][j] = fmaf(s0, vv[j], acc[0][j]);
                    acc[1][j] = fmaf(s1, vv[j], acc[1][j]);
                    acc[2][j] = fmaf(s2, vv[j], acc[2][j]);
                    acc[3][j] = fmaf(s3, vv[j], acc[3][j]);
                }
                pl += 16;
            }
            // post-hoc fix of position cur: acc += S[cur]*(vn - v_cached)
            if (cur >= p0 && cur < pend && pt == ((cur - p0) & 15)) {
                const float* vc = cache_v + base + (size_t)cur * D + d0;
                const float4 a = *(const float4*)vc;
                const float4 cc = *(const float4*)(vc + 4);
                const float vv[8] = {a.x, a.y, a.z, a.w, cc.x, cc.y, cc.z, cc.w};
                const int pl2 = cur - p0;
                const float s0 = S[0 * CLEN + pl2], s1 = S[1 * CLEN + pl2];
                const float s2 = S[2 * CLEN + pl2], s3 = S[3 * CLEN + pl2];
#pragma unroll
                for (int j = 0; j < 8; ++j) {
                    const float dv = vn[d0 + j] - vv[j];
                    acc[0][j] = fmaf(s0, dv, acc[0][j]);
                    acc[1][j] = fmaf(s1, dv, acc[1][j]);
                    acc[2][j] = fmaf(s2, dv, acc[2][j]);
                    acc[3][j] = fmaf(s3, dv, acc[3][j]);
                }
            }
        } else {
            float vn8[8];
#pragma unroll
            for (int j = 0; j < 8; ++j) vn8[j] = vn[d0 + j];
            for (int i = 0; i < CLEN / 16; ++i) {
                const int p = p0 + i * 16 + pt;
                if (p < pend) {
                    const float4 a = *(const float4*)(cache_v + base + (size_t)p * D + d0);
                    const float4 cc = *(const float4*)(cache_v + base + (size_t)p * D + d0 + 4);
                    float vv[8] = {a.x, a.y, a.z, a.w, cc.x, cc.y, cc.z, cc.w};
                    if (p == cur) {
#pragma unroll
                        for (int j = 0; j < 8; ++j) vv[j] = vn8[j];
                    }
                    const int pl = p - p0;
                    const float s0 = S[0 * CLEN + pl], s1 = S[1 * CLEN + pl];
                    const float s2 = S[2 * CLEN + pl], s3 = S[3 * CLEN + pl];
#pragma unroll
                    for (int j = 0; j < 8; ++j) {
                        acc[0][j] = fmaf(s0, vv[j], acc[0][j]);
                        acc[1][j] = fmaf(s1, vv[j], acc[1][j]);
                        acc[2][j] = fmaf(s2, vv[j], acc[2][j]);
                        acc[3][j] = fmaf(s3, vv[j], acc[3][j]);
                    }
                }
            }
        }
        // reduce over the 4 in-wave pt-groups (lane bits 4,5)
#pragma unroll
        for (int off = 16; off <= 32; off <<= 1)
#pragma unroll
            for (int g = 0; g < 4; ++g)
#pragma unroll
                for (int j = 0; j < 8; ++j)
                    acc[g][j] += __shfl_xor(acc[g][j], off, 64);
        if (l < 16) {
#pragma unroll
            for (int g = 0; g < 4; ++g)
#pragma unroll
                for (int j = 0; j < 8; ++j)
                    red[(w * 4 + g) * D + l * 8 + j] = acc[g][j];
        }
    }
    __syncthreads();

    {   // cross-wave reduce + write partials (each thread covers 2 heads)
        const int d = t & 127, half = t >> 7;
#pragma unroll
        for (int gi = 0; gi < 2; ++gi) {
            const int g = half + gi * 2;
            float sum = 0.f;
#pragma unroll
            for (int w4 = 0; w4 < 4; ++w4) sum += red[(w4 * 4 + g) * D + d];
            const int hidx = bkv * GQ + g;
            pacc[((size_t)hidx * NCHK + c) * D + d] = sum;
            if (d == 0) {
                pm[hidx * NCHK + c]   = sm_m[g];
                psum[hidx * NCHK + c] = sm_s[g];
            }
        }
    }
}

// ------- combine partial chunks: one block per (b, kv), 512 threads -------
__global__ __launch_bounds__(512) void k_attn_combine(
        const float* __restrict__ pacc, const float* __restrict__ pm,
        const float* __restrict__ psum, float* __restrict__ attn_out) {
    const int t = threadIdx.x;
    const int bkv = blockIdx.x;
    const int b = bkv >> 3, kv = bkv & 7;
    const int g = t >> 7, d = t & 127;
    const int hidx = bkv * GQ + g;

    float mm[NCHK];
    float m = -1e30f;
#pragma unroll
    for (int c = 0; c < NCHK; ++c) {
        mm[c] = pm[hidx * NCHK + c];
        m = fmaxf(m, mm[c]);
    }
    float tot = 0.f, acc = 0.f;
#pragma unroll
    for (int c = 0; c < NCHK; ++c) {
        const float wgt = __expf(mm[c] - m);
        tot = fmaf(psum[hidx * NCHK + c], wgt, tot);
        acc = fmaf(pacc[((size_t)hidx * NCHK + c) * D + d], wgt, acc);
    }
    attn_out[(size_t)b * HID + (kv * GQ + g) * D + d] = acc / tot;
}

// ---------------- host launch ----------------
extern "C" void kernel_launch(void* const* d_in, const int* in_sizes, int n_in,
                              void* d_out, int out_size, void* d_ws, size_t ws_size,
                              hipStream_t stream) {
    const float* x    = (const float*)d_in[0];
    const float* wqkv = (const float*)d_in[1];
    const float* wo   = (const float*)d_in[2];
    const float* rot  = (const float*)d_in[3];
    const float* ck   = (const float*)d_in[4];
    const float* cv   = (const float*)d_in[5];
    const int*   sp   = (const int*)d_in[6];
    const int*   cp   = (const int*)d_in[7];

    float* ws     = (float*)d_ws;
    float* q_rot  = ws;                     // 32*32*128 = 131072
    float* k_rot  = ws + 131072;            // 32*8*128  = 32768
    float* v_new  = ws + 163840;            // 32*8*128  = 32768
    float* attn_o = ws + 196608;            // 32*4096   = 131072
    float* part   = ws + 327680;            // NCH*32*6144 = 3145728 (GEMM partials)
    // attention partials alias the part region (disjoint in time):
    float* pacc   = part;                   // 1024*8*128 = 1048576
    float* pm     = part + 1048576;         // 8192
    float* psum   = part + 1056768;         // 8192

    k_gemm_split<EQKV><<<dim3(EQKV / 128, NCH), 256, 0, stream>>>(x, wqkv, part);
    k_finish<<<32 * 48, 128, 0, stream>>>(part, rot, q_rot, k_rot, v_new);
    k_attn_part<<<256 * NCHK, 256, 0, stream>>>(q_rot, k_rot, v_new, ck, cv,
                                                sp, cp, pacc, pm, psum);
    k_attn_combine<<<256, 512, 0, stream>>>(pacc, pm, psum, attn_o);
    k_gemm_split<HID><<<dim3(HID / 128, NCH), 256, 0, stream>>>(attn_o, wo, part);
    k_reduce_f32<<<128, 256, 0, stream>>>(part, (float*)d_out, 32 * HID);
}